// Round 1
// baseline (220.872 us; speedup 1.0000x reference)
//
#include <hip/hip_runtime.h>

// Chamfer 2D: B=4, N=M=8192, D=2.
// Out layout (flat float32): dist1[B*N] | dist2[B*M] | idx1[B*N] | idx2[B*M]
// idx written as float values (harness reads whole out buffer as float32).

#define BB 4
#define NN 8192
#define MM 8192

// blocks 0..127: dir1 (query=in1, ref=in2); 128..255: dir2 (query=in2, ref=in1)
// 32 blocks per batch (8192/256).
__global__ __launch_bounds__(256, 1) void chamfer_kernel(
    const float* __restrict__ in1, const float* __restrict__ in2,
    float* __restrict__ out)
{
    const int bid  = blockIdx.x;
    const int dir2 = (bid >= (BB * NN / 256)) ? 1 : 0;
    const int lbid = dir2 ? (bid - (BB * NN / 256)) : bid;
    const int b    = lbid >> 5;                       // batch (scalar)
    const int i    = ((lbid & 31) << 8) + threadIdx.x; // query index in [0,8192)

    const float* __restrict__ Qb = (dir2 ? in2 : in1) + (size_t)b * NN * 2;
    const float* __restrict__ P  = (dir2 ? in1 : in2) + (size_t)b * MM * 2; // wave-uniform

    const float2 q = *(const float2*)(Qb + (size_t)i * 2);
    const float qx = q.x, qy = q.y;

    // 4 independent min-chains to break the serial min dependency.
    float best[4] = {1e30f, 1e30f, 1e30f, 1e30f};
    int   bidx[4] = {0, 0, 0, 0};

    for (int j = 0; j < MM; j += 8) {
#pragma unroll
        for (int u = 0; u < 8; ++u) {
            // P[...] has a wave-uniform address -> scalar loads (s_load),
            // keeping the vector pipe free for the distance math.
            const float px = P[2 * (j + u) + 0];
            const float py = P[2 * (j + u) + 1];
            const float dx = qx - px;
            const float dy = qy - py;
            // Exact same rounding as numpy: (dx*dx) + (dy*dy), no FMA contraction,
            // so distances bit-match the reference and argmin picks identical indices.
            const float d = __fadd_rn(__fmul_rn(dx, dx), __fmul_rn(dy, dy));
            const int k = u & 3;
            const bool c = d < best[k];       // strict < keeps first occurrence
            best[k] = c ? d : best[k];
            bidx[k] = c ? (j + u) : bidx[k];
        }
    }

    // Combine chains: min value, ties -> smallest index (matches np.argmin).
    float bv = best[0]; int bi = bidx[0];
#pragma unroll
    for (int k = 1; k < 4; ++k) {
        const bool take = (best[k] < bv) || (best[k] == bv && bidx[k] < bi);
        bv = take ? best[k] : bv;
        bi = take ? bidx[k] : bi;
    }

    const size_t o = (size_t)b * 8192 + (size_t)i;
    if (!dir2) {
        out[o]                     = bv;        // dist1
        out[2 * (size_t)BB * 8192 + o] = (float)bi; // idx1 at offset 65536
    } else {
        out[(size_t)BB * 8192 + o]     = bv;        // dist2 at offset 32768
        out[3 * (size_t)BB * 8192 + o] = (float)bi; // idx2 at offset 98304
    }
}

extern "C" void kernel_launch(void* const* d_in, const int* in_sizes, int n_in,
                              void* d_out, int out_size, void* d_ws, size_t ws_size,
                              hipStream_t stream) {
    const float* in1 = (const float*)d_in[0];
    const float* in2 = (const float*)d_in[1];
    float* out = (float*)d_out;
    (void)in_sizes; (void)n_in; (void)out_size; (void)d_ws; (void)ws_size;

    const int total_blocks = (BB * NN + BB * MM) / 256; // 256
    chamfer_kernel<<<total_blocks, 256, 0, stream>>>(in1, in2, out);
}

// Round 2
// 98.612 us; speedup vs baseline: 2.2398x; 2.2398x over previous
//
#include <hip/hip_runtime.h>

// Chamfer 2D: B=4, N=M=8192, D=2.
// Out layout (flat float32): dist1[B*N] | dist2[B*M] | idx1[B*N] | idx2[B*M]
// idx written as float values (harness reads whole out buffer as float32).
//
// R2: split the 8192-point reference loop into SPLIT=8 chunks to raise
// occupancy from 1 wave/SIMD to 8 waves/SIMD (R1 showed VALUBusy 30% /
// Occupancy 11.6% -> latency-bound). Partials (min,argmin) per chunk go to
// d_ws; a small second kernel reduces 8 partials/output with tie-break to
// the lower chunk (preserves np.argmin first-occurrence semantics).

#define BB 4
#define NN 8192
#define MM 8192
#define SPLIT 8
#define CHUNK (MM / SPLIT)   // 1024

// ---- partial kernel: 2048 blocks ----------------------------------------
// bid = ((dir*BB + b)*32 + iblk)*SPLIT + chunk
__global__ __launch_bounds__(256, 8) void chamfer_partial_kernel(
    const float* __restrict__ in1, const float* __restrict__ in2,
    float* __restrict__ ws_dist, int* __restrict__ ws_idx)
{
    const int bid   = blockIdx.x;
    const int chunk = bid & (SPLIT - 1);
    const int rem   = bid >> 3;            // (dir*BB + b)*32 + iblk
    const int iblk  = rem & 31;
    const int db    = rem >> 5;            // dir*BB + b
    const int dir2  = db >> 2;
    const int b     = db & 3;

    const int i = (iblk << 8) + threadIdx.x;       // query index in [0,8192)

    const float* __restrict__ Qb = (dir2 ? in2 : in1) + (size_t)b * NN * 2;
    const float* __restrict__ P  = (dir2 ? in1 : in2) + (size_t)b * MM * 2; // wave-uniform

    const float2 q = *(const float2*)(Qb + (size_t)i * 2);
    const float qx = q.x, qy = q.y;

    const int j0 = chunk * CHUNK;

    // 4 independent min-chains to break the serial min dependency.
    float best[4] = {1e30f, 1e30f, 1e30f, 1e30f};
    int   bidx[4] = {j0, j0, j0, j0};

    for (int j = j0; j < j0 + CHUNK; j += 8) {
#pragma unroll
        for (int u = 0; u < 8; ++u) {
            // Wave-uniform address -> scalar loads (s_load), VALU stays free.
            const float px = P[2 * (j + u) + 0];
            const float py = P[2 * (j + u) + 1];
            const float dx = qx - px;
            const float dy = qy - py;
            // Exact same rounding as numpy: (dx*dx)+(dy*dy), no FMA contraction,
            // so distances bit-match the reference and argmin is identical.
            const float d = __fadd_rn(__fmul_rn(dx, dx), __fmul_rn(dy, dy));
            const int k = u & 3;
            const bool c = d < best[k];      // strict < keeps first occurrence
            best[k] = c ? d : best[k];
            bidx[k] = c ? (j + u) : bidx[k];
        }
    }

    // Combine chains: min value, ties -> smallest index (matches np.argmin).
    float bv = best[0]; int bi = bidx[0];
#pragma unroll
    for (int k = 1; k < 4; ++k) {
        const bool take = (best[k] < bv) || (best[k] == bv && bidx[k] < bi);
        bv = take ? best[k] : bv;
        bi = take ? bidx[k] : bi;
    }

    const size_t pbase = (((size_t)db * 8192 + i) * SPLIT) + chunk;
    ws_dist[pbase] = bv;
    ws_idx[pbase]  = bi;
}

// ---- reduction kernel: 65536 threads ------------------------------------
__global__ __launch_bounds__(256) void chamfer_reduce_kernel(
    const float* __restrict__ ws_dist, const int* __restrict__ ws_idx,
    float* __restrict__ out)
{
    const int o = blockIdx.x * 256 + threadIdx.x;   // [0, 2*BB*8192)
    if (o >= 2 * BB * 8192) return;
    const int dir2 = o >> 15;                       // 32768 per dir
    const int od   = o & 32767;                     // b*8192 + i

    const size_t pbase = (size_t)o * SPLIT;
    float bv = ws_dist[pbase];
    int   bi = ws_idx[pbase];
#pragma unroll
    for (int c = 1; c < SPLIT; ++c) {
        const float dv = ws_dist[pbase + c];
        const int   iv = ws_idx[pbase + c];
        // strict <: lower chunk wins ties -> smaller index -> first occurrence
        const bool take = dv < bv;
        bv = take ? dv : bv;
        bi = take ? iv : bi;
    }

    if (!dir2) {
        out[od]         = bv;            // dist1
        out[65536 + od] = (float)bi;     // idx1
    } else {
        out[32768 + od] = bv;            // dist2
        out[98304 + od] = (float)bi;     // idx2
    }
}

// ---- fallback single-pass kernel (R1 structure) if ws too small ----------
__global__ __launch_bounds__(256, 1) void chamfer_single_kernel(
    const float* __restrict__ in1, const float* __restrict__ in2,
    float* __restrict__ out)
{
    const int bid  = blockIdx.x;
    const int dir2 = (bid >= (BB * NN / 256)) ? 1 : 0;
    const int lbid = dir2 ? (bid - (BB * NN / 256)) : bid;
    const int b    = lbid >> 5;
    const int i    = ((lbid & 31) << 8) + threadIdx.x;

    const float* __restrict__ Qb = (dir2 ? in2 : in1) + (size_t)b * NN * 2;
    const float* __restrict__ P  = (dir2 ? in1 : in2) + (size_t)b * MM * 2;

    const float2 q = *(const float2*)(Qb + (size_t)i * 2);
    const float qx = q.x, qy = q.y;

    float best[4] = {1e30f, 1e30f, 1e30f, 1e30f};
    int   bidx[4] = {0, 0, 0, 0};

    for (int j = 0; j < MM; j += 8) {
#pragma unroll
        for (int u = 0; u < 8; ++u) {
            const float px = P[2 * (j + u) + 0];
            const float py = P[2 * (j + u) + 1];
            const float dx = qx - px;
            const float dy = qy - py;
            const float d = __fadd_rn(__fmul_rn(dx, dx), __fmul_rn(dy, dy));
            const int k = u & 3;
            const bool c = d < best[k];
            best[k] = c ? d : best[k];
            bidx[k] = c ? (j + u) : bidx[k];
        }
    }

    float bv = best[0]; int bi = bidx[0];
#pragma unroll
    for (int k = 1; k < 4; ++k) {
        const bool take = (best[k] < bv) || (best[k] == bv && bidx[k] < bi);
        bv = take ? best[k] : bv;
        bi = take ? bidx[k] : bi;
    }

    const size_t o = (size_t)b * 8192 + (size_t)i;
    if (!dir2) {
        out[o]          = bv;
        out[65536 + o]  = (float)bi;
    } else {
        out[32768 + o]  = bv;
        out[98304 + o]  = (float)bi;
    }
}

extern "C" void kernel_launch(void* const* d_in, const int* in_sizes, int n_in,
                              void* d_out, int out_size, void* d_ws, size_t ws_size,
                              hipStream_t stream) {
    const float* in1 = (const float*)d_in[0];
    const float* in2 = (const float*)d_in[1];
    float* out = (float*)d_out;
    (void)in_sizes; (void)n_in; (void)out_size;

    const size_t n_part = (size_t)2 * BB * 8192 * SPLIT;        // 524288
    const size_t ws_need = n_part * (sizeof(float) + sizeof(int)); // 4 MB

    if (ws_size >= ws_need) {
        float* ws_dist = (float*)d_ws;
        int*   ws_idx  = (int*)((char*)d_ws + n_part * sizeof(float));
        chamfer_partial_kernel<<<2 * BB * 32 * SPLIT, 256, 0, stream>>>(
            in1, in2, ws_dist, ws_idx);
        chamfer_reduce_kernel<<<(2 * BB * 8192) / 256, 256, 0, stream>>>(
            ws_dist, ws_idx, out);
    } else {
        chamfer_single_kernel<<<(BB * NN + BB * MM) / 256, 256, 0, stream>>>(
            in1, in2, out);
    }
}